// Round 6
// baseline (203.667 us; speedup 1.0000x reference)
//
#include <hip/hip_runtime.h>

#define BB 4
#define NN 2048
#define DD 4
#define QQ (NN / 4)          // 512 quads along j
#define BLOCK 512            // 8 waves/block, one row per wave per half
#define JIT 8                // j-iterations per lane per half
#define GRID 512             // exactly resident: 2 blocks/CU * 256 CU

typedef float f4 __attribute__((ext_vector_type(4)));
typedef _Float16 h2 __attribute__((ext_vector_type(2)));

#if __has_builtin(__builtin_amdgcn_fdot2) && __has_builtin(__builtin_amdgcn_cvt_pkrtz)
#define USE_FDOT2 1
#endif

static __device__ __forceinline__ unsigned pack_sc(float s, float c) {
#ifdef USE_FDOT2
    return __builtin_bit_cast(unsigned, __builtin_amdgcn_cvt_pkrtz(s, c));
#else
    h2 p; p[0] = (_Float16)s; p[1] = (_Float16)c;
    return __builtin_bit_cast(unsigned, p);
#endif
}

// ---------------- persistent fused kernel: 512 blocks (exactly resident), 8 waves/block.
// Each block handles TWO 8-row groups of the SAME batch (e and e+128): one sincos
// table build serves both, and the rotating depth-2 prefetch runs continuously across
// the half boundary (group B's first tiles issue during group A's last iterations),
// so the second half has zero cold-start. Single generation -> one dispatch ramp.
__global__ __launch_bounds__(BLOCK, 4) void kuramoto_fused(
    const float* __restrict__ theta,
    const float* __restrict__ gam,
    const float* __restrict__ aff,
    const float* __restrict__ alp,
    const float* __restrict__ omega,
    const float* __restrict__ kappa,
    const float* __restrict__ bias,
    float* __restrict__ out)
{
    // XCD swizzle: batch-siblings x, x+8, x+16, x+24 share row-group e, differ in
    // batch b, same XCD (x%8) close in time -> bias-row L2 reuse.
    const int x   = blockIdx.x;                          // [0, 512)
    const int low = x & 31;
    const int b   = low >> 3;
    const int e   = (x >> 5) * 8 + (low & 7);            // [0, 128)

    const int tid  = threadIdx.x;
    const int wave = tid >> 6;                           // [0, 8)
    const int lane = tid & 63;
    const int iA   = e * 8 + wave;                       // half-A row
    const int iB   = (e + 128) * 8 + wave;               // half-B row

    const f4* abase = (const f4*)(aff + (size_t)b * NN * NN);
    const f4* lbase = (const f4*)(alp + (size_t)b * NN * NN);
    const f4* bbase = (const f4*)bias;
    const f4* arowA = abase + (size_t)iA * QQ;
    const f4* lrowA = lbase + (size_t)iA * QQ;
    const f4* browA = bbase + (size_t)iA * QQ;
    const f4* arowB = abase + (size_t)iB * QQ;
    const f4* lrowB = lbase + (size_t)iB * QQ;
    const f4* browB = bbase + (size_t)iB * QQ;

    // ---- issue half-A tiles 0,1 early: latency hides under the sincos table build ----
    f4 av[3], lv[3], bv[3];
    av[0] = __builtin_nontemporal_load(&arowA[lane]);
    lv[0] = __builtin_nontemporal_load(&lrowA[lane]);
    bv[0] = browA[lane];
    av[1] = __builtin_nontemporal_load(&arowA[lane + 64]);
    lv[1] = __builtin_nontemporal_load(&lrowA[lane + 64]);
    bv[1] = browA[lane + 64];

    // ---- build this batch's sincos table in LDS (32 KB), one quad per thread ----
    // entry (d, q) = 4 fp16 (s,c) pairs for j = 4q..4q+3; each 32-bit word is a
    // ready-made v_dot2_f32_f16 operand {sin(θj), cos(θj)}.
    __shared__ uint4 lsc[4 * QQ];
    const f4* theta4 = (const f4*)theta + (size_t)b * NN;
    {
        const int q = tid;                               // QQ == BLOCK
        float s[4][4], c[4][4];                          // [u][d]
        #pragma unroll
        for (int u = 0; u < 4; ++u) {
            const f4 th = theta4[4 * q + u];
            #pragma unroll
            for (int d = 0; d < 4; ++d) __sincosf(th[d], &s[u][d], &c[u][d]);
        }
        #pragma unroll
        for (int d = 0; d < 4; ++d) {
            uint4 w;
            w.x = pack_sc(s[0][d], c[0][d]);
            w.y = pack_sc(s[1][d], c[1][d]);
            w.z = pack_sc(s[2][d], c[2][d]);
            w.w = pack_sc(s[3][d], c[3][d]);
            lsc[d * QQ + q] = w;
        }
    }
    __syncthreads();

    f4 accUA = {0.f, 0.f, 0.f, 0.f}, accVA = {0.f, 0.f, 0.f, 0.f};
    f4 accUB = {0.f, 0.f, 0.f, 0.f}, accVB = {0.f, 0.f, 0.f, 0.f};

    // ---- 16 fully-unrolled steps: t<8 = half A, t>=8 = half B.
    // All buffer/half selections are compile-time constants under the unroll.
    #pragma unroll
    for (int t = 0; t < 2 * JIT; ++t) {
        const int cur = t % 3;
        const int q   = lane + 64 * (t & 7);

        if (t + 2 < 2 * JIT) {
            const int tq = t + 2;
            const int nx = tq % 3;
            const int qn = lane + 64 * (tq & 7);
            const f4* pa = (tq < JIT) ? arowA : arowB;   // compile-time select
            const f4* pl = (tq < JIT) ? lrowA : lrowB;
            const f4* pb = (tq < JIT) ? browA : browB;
            av[nx] = __builtin_nontemporal_load(&pa[qn]);
            lv[nx] = __builtin_nontemporal_load(&pl[qn]);
            bv[nx] = pb[qn];
        }

        // (s,c) fp16 pairs for this quad, one b128 per d.
        const uint4 w0 = lsc[0 * QQ + q];
        const uint4 w1 = lsc[1 * QQ + q];
        const uint4 w2 = lsc[2 * QQ + q];
        const uint4 w3 = lsc[3 * QQ + q];
        const unsigned wq[4][4] = {
            {w0.x, w0.y, w0.z, w0.w},
            {w1.x, w1.y, w1.z, w1.w},
            {w2.x, w2.y, w2.z, w2.w},
            {w3.x, w3.y, w3.z, w3.w},
        };

        f4& aU = (t < JIT) ? accUA : accUB;              // compile-time select
        f4& aV = (t < JIT) ? accVA : accVB;

        const f4 alr = lv[cur] + bv[cur];
        const f4 af  = av[cur];
        #pragma unroll
        for (int u = 0; u < 4; ++u) {
            float sa, ca;
            __sincosf(alr[u], &sa, &ca);
            const float wc = af[u] * ca;
            const float ws = af[u] * sa;
#ifdef USE_FDOT2
            // aU[d] += wc*s - ws*c ; aV[d] += ws*s + wc*c
            const h2 pw = __builtin_bit_cast(h2, __builtin_amdgcn_cvt_pkrtz(wc, -ws));
            const h2 pv = __builtin_bit_cast(h2, __builtin_amdgcn_cvt_pkrtz(ws,  wc));
            #pragma unroll
            for (int d = 0; d < 4; ++d) {
                const h2 pr = __builtin_bit_cast(h2, wq[d][u]);
                aU[d] = __builtin_amdgcn_fdot2(pw, pr, aU[d], false);
                aV[d] = __builtin_amdgcn_fdot2(pv, pr, aV[d], false);
            }
#else
            #pragma unroll
            for (int d = 0; d < 4; ++d) {
                const h2 pr = __builtin_bit_cast(h2, wq[d][u]);
                const float sj = (float)pr[0];
                const float cj = (float)pr[1];
                aU[d] += wc * sj - ws * cj;
                aV[d] += wc * cj + ws * sj;
            }
#endif
        }
    }

    // ---- wave-local shuffle reductions; no barrier needed ----
    #pragma unroll
    for (int off = 32; off >= 1; off >>= 1) {
        #pragma unroll
        for (int d = 0; d < 4; ++d) {
            accUA[d] += __shfl_down(accUA[d], off, 64);
            accVA[d] += __shfl_down(accVA[d], off, 64);
            accUB[d] += __shfl_down(accUB[d], off, 64);
            accVB[d] += __shfl_down(accVB[d], off, 64);
        }
    }

    if (lane == 0) {
        const f4* gam4 = (const f4*)gam;
        const f4* om4  = (const f4*)omega;
        const f4* kp4  = (const f4*)kappa;
        f4* out4       = (f4*)out;

        #pragma unroll
        for (int h = 0; h < 2; ++h) {
            const int i    = h ? iB : iA;
            const f4  aU   = h ? accUB : accUA;
            const f4  aV   = h ? accVB : accVA;
            const size_t base = (size_t)b * NN + i;
            const f4 th = theta4[i];                     // theta4 already offset by b*NN
            const f4 gm = gam4[base];
            const f4 om = om4[i];
            const f4 kp = kp4[i];
            f4 o;
            #pragma unroll
            for (int d = 0; d < 4; ++d) {
                float si, ci;
                __sincosf(th[d], &si, &ci);              // fp32 epilogue sincos, inline
                const float coup = (1.0f / (float)NN) * (ci * aU[d] - si * aV[d]);
                o[d] = th[d] + om[d] + kp[d] * (gm[d] - th[d]) + coup;
            }
            out4[base] = o;
        }
    }
}

extern "C" void kernel_launch(void* const* d_in, const int* in_sizes, int n_in,
                              void* d_out, int out_size, void* d_ws, size_t ws_size,
                              hipStream_t stream) {
    const float* theta = (const float*)d_in[0];
    const float* gam   = (const float*)d_in[1];
    const float* aff   = (const float*)d_in[2];
    const float* alp   = (const float*)d_in[3];
    const float* omega = (const float*)d_in[4];
    const float* kappa = (const float*)d_in[5];
    const float* bias  = (const float*)d_in[6];
    float* out  = (float*)d_out;
    (void)d_ws; (void)ws_size;                           // workspace not used

    kuramoto_fused<<<GRID, BLOCK, 0, stream>>>(
        theta, gam, aff, alp, omega, kappa, bias, out);
}

// Round 7
// 174.371 us; speedup vs baseline: 1.1680x; 1.1680x over previous
//
#include <hip/hip_runtime.h>

#define BB 4
#define NN 2048
#define DD 4
#define QQ (NN / 4)          // 512 quads along j
#define BLOCK 512            // 8 waves/block, 8 rows/block
#define JIT (QQ / 64)        // 8 j-iterations per lane

typedef float f4 __attribute__((ext_vector_type(4)));
typedef _Float16 h2 __attribute__((ext_vector_type(2)));

#if __has_builtin(__builtin_amdgcn_fdot2) && __has_builtin(__builtin_amdgcn_cvt_pkrtz)
#define USE_FDOT2 1
#endif

static __device__ __forceinline__ unsigned pack_sc(float s, float c) {
#ifdef USE_FDOT2
    return __builtin_bit_cast(unsigned, __builtin_amdgcn_cvt_pkrtz(s, c));
#else
    h2 p; p[0] = (_Float16)s; p[1] = (_Float16)c;
    return __builtin_bit_cast(unsigned, p);
#endif
}

// ---------------- single fused kernel: 1024 blocks, 8 waves/block, one row per wave.
// ALL 1024 blocks are co-resident (4 blocks/CU x 256 CU): LDS 32KB -> 5/CU, waves
// 32/CU -> 4/CU, VGPR<=64 (pinned by launch_bounds(512,8)) -> 8 waves/SIMD.
// Round-6 lesson: dropping to 2 blocks/CU cost +37 us (2.95 TB/s vs ~4 TB/s) -- this
// kernel is read-stream parallelism-bound; occupancy is the first-order lever.
// Depth-2 rotating prefetch; two tiles issued before the sincos table build so HBM
// latency hides under the VALU phase. Depth stays 2: depth-3 pushes VGPR>64 and
// halves waves/SIMD.
__global__ __launch_bounds__(BLOCK, 8) void kuramoto_fused(
    const float* __restrict__ theta,
    const float* __restrict__ gam,
    const float* __restrict__ aff,
    const float* __restrict__ alp,
    const float* __restrict__ omega,
    const float* __restrict__ kappa,
    const float* __restrict__ bias,
    float* __restrict__ out)
{
    // XCD swizzle: batch-siblings x, x+8, x+16, x+24 share row-group g, differ in
    // batch b, and land on the same XCD (x%8) close in time -> bias-row L2 reuse.
    const int x   = blockIdx.x;                          // [0, 1024)
    const int low = x & 31;
    const int b   = low >> 3;
    const int g   = (x >> 5) * 8 + (low & 7);            // row-group [0, 256)
    const int i0  = g * 8;

    const int tid  = threadIdx.x;
    const int wave = tid >> 6;                           // [0, 8)
    const int lane = tid & 63;
    const int i    = i0 + wave;                          // this wave's row

    const f4* arow = (const f4*)(aff + (size_t)b * NN * NN) + (size_t)i * QQ;
    const f4* lrow = (const f4*)(alp + (size_t)b * NN * NN) + (size_t)i * QQ;
    const f4* brow = (const f4*)bias + (size_t)i * QQ;

    // ---- issue tiles 0 and 1 early: latency hides under the sincos table build ----
    f4 av[3], lv[3], bv[3];
    av[0] = __builtin_nontemporal_load(&arow[lane]);
    lv[0] = __builtin_nontemporal_load(&lrow[lane]);
    bv[0] = brow[lane];
    av[1] = __builtin_nontemporal_load(&arow[lane + 64]);
    lv[1] = __builtin_nontemporal_load(&lrow[lane + 64]);
    bv[1] = brow[lane + 64];

    // ---- build this batch's sincos table in LDS (32 KB), one quad per thread ----
    // entry (d, q) = 4 fp16 (s,c) pairs for j = 4q..4q+3; each 32-bit word is a
    // ready-made v_dot2_f32_f16 operand {sin(θj), cos(θj)}.
    __shared__ uint4 lsc[4 * QQ];
    const f4* theta4 = (const f4*)theta + (size_t)b * NN;
    {
        const int q = tid;                               // QQ == BLOCK
        float s[4][4], c[4][4];                          // [u][d]
        #pragma unroll
        for (int u = 0; u < 4; ++u) {
            const f4 th = theta4[4 * q + u];
            #pragma unroll
            for (int d = 0; d < 4; ++d) __sincosf(th[d], &s[u][d], &c[u][d]);
        }
        #pragma unroll
        for (int d = 0; d < 4; ++d) {
            uint4 w;
            w.x = pack_sc(s[0][d], c[0][d]);
            w.y = pack_sc(s[1][d], c[1][d]);
            w.z = pack_sc(s[2][d], c[2][d]);
            w.w = pack_sc(s[3][d], c[3][d]);
            lsc[d * QQ + q] = w;
        }
    }
    __syncthreads();

    f4 accU = {0.f, 0.f, 0.f, 0.f};
    f4 accV = {0.f, 0.f, 0.f, 0.f};

    #pragma unroll
    for (int jj = 0; jj < JIT; ++jj) {                   // fully unrolled: all
        const int cur = jj % 3;                          // buffer indices static
        const int q   = lane + 64 * jj;

        if (jj + 2 < JIT) {
            const int nx = (jj + 2) % 3;
            const int qn = q + 128;
            av[nx] = __builtin_nontemporal_load(&arow[qn]);
            lv[nx] = __builtin_nontemporal_load(&lrow[qn]);
            bv[nx] = brow[qn];
        }

        // (s,c) fp16 pairs for this quad, one b128 per d.
        const uint4 w0 = lsc[0 * QQ + q];
        const uint4 w1 = lsc[1 * QQ + q];
        const uint4 w2 = lsc[2 * QQ + q];
        const uint4 w3 = lsc[3 * QQ + q];
        const unsigned wq[4][4] = {
            {w0.x, w0.y, w0.z, w0.w},
            {w1.x, w1.y, w1.z, w1.w},
            {w2.x, w2.y, w2.z, w2.w},
            {w3.x, w3.y, w3.z, w3.w},
        };

        const f4 alr = lv[cur] + bv[cur];
        const f4 af  = av[cur];
        #pragma unroll
        for (int u = 0; u < 4; ++u) {
            float sa, ca;
            __sincosf(alr[u], &sa, &ca);
            const float wc = af[u] * ca;
            const float ws = af[u] * sa;
#ifdef USE_FDOT2
            // accU[d] += wc*s - ws*c ; accV[d] += ws*s + wc*c
            const h2 pw = __builtin_bit_cast(h2, __builtin_amdgcn_cvt_pkrtz(wc, -ws));
            const h2 pv = __builtin_bit_cast(h2, __builtin_amdgcn_cvt_pkrtz(ws,  wc));
            #pragma unroll
            for (int d = 0; d < 4; ++d) {
                const h2 pr = __builtin_bit_cast(h2, wq[d][u]);
                accU[d] = __builtin_amdgcn_fdot2(pw, pr, accU[d], false);
                accV[d] = __builtin_amdgcn_fdot2(pv, pr, accV[d], false);
            }
#else
            #pragma unroll
            for (int d = 0; d < 4; ++d) {
                const h2 pr = __builtin_bit_cast(h2, wq[d][u]);
                const float sj = (float)pr[0];
                const float cj = (float)pr[1];
                accU[d] += wc * sj - ws * cj;
                accV[d] += wc * cj + ws * sj;
            }
#endif
        }
    }

    // ---- wave-local shuffle reduction; no barrier needed ----
    #pragma unroll
    for (int off = 32; off >= 1; off >>= 1) {
        #pragma unroll
        for (int d = 0; d < 4; ++d) {
            accU[d] += __shfl_down(accU[d], off, 64);
            accV[d] += __shfl_down(accV[d], off, 64);
        }
    }

    if (lane == 0) {
        const f4* gam4 = (const f4*)gam;
        const f4* om4  = (const f4*)omega;
        const f4* kp4  = (const f4*)kappa;
        f4* out4       = (f4*)out;

        const size_t base = (size_t)b * NN + i;
        const f4 th = theta4[i];                         // theta4 already offset by b*NN
        const f4 gm = gam4[base];
        const f4 om = om4[i];
        const f4 kp = kp4[i];
        f4 o;
        #pragma unroll
        for (int d = 0; d < 4; ++d) {
            float si, ci;
            __sincosf(th[d], &si, &ci);                  // fp32 epilogue sincos, inline
            const float coup = (1.0f / (float)NN) * (ci * accU[d] - si * accV[d]);
            o[d] = th[d] + om[d] + kp[d] * (gm[d] - th[d]) + coup;
        }
        out4[base] = o;
    }
}

extern "C" void kernel_launch(void* const* d_in, const int* in_sizes, int n_in,
                              void* d_out, int out_size, void* d_ws, size_t ws_size,
                              hipStream_t stream) {
    const float* theta = (const float*)d_in[0];
    const float* gam   = (const float*)d_in[1];
    const float* aff   = (const float*)d_in[2];
    const float* alp   = (const float*)d_in[3];
    const float* omega = (const float*)d_in[4];
    const float* kappa = (const float*)d_in[5];
    const float* bias  = (const float*)d_in[6];
    float* out  = (float*)d_out;
    (void)d_ws; (void)ws_size;                           // workspace not used

    kuramoto_fused<<<BB * (NN / 8), BLOCK, 0, stream>>>(
        theta, gam, aff, alp, omega, kappa, bias, out);
}

// Round 8
// 168.423 us; speedup vs baseline: 1.2093x; 1.0353x over previous
//
#include <hip/hip_runtime.h>

#define BB 4
#define NN 2048
#define DD 4
#define QQ (NN / 4)          // 512 quads along j
#define BLOCK 512            // 8 waves/block, 8 rows/block
#define WPB 8                // waves per block
#define JIT (QQ / 64)        // 8 j-iterations per lane

typedef float f4 __attribute__((ext_vector_type(4)));
typedef _Float16 h2 __attribute__((ext_vector_type(2)));

#if __has_builtin(__builtin_amdgcn_fdot2) && __has_builtin(__builtin_amdgcn_cvt_pkrtz)
#define USE_FDOT2 1
#endif

static __device__ __forceinline__ unsigned pack_sc(float s, float c) {
#ifdef USE_FDOT2
    return __builtin_bit_cast(unsigned, __builtin_amdgcn_cvt_pkrtz(s, c));
#else
    h2 p; p[0] = (_Float16)s; p[1] = (_Float16)c;
    return __builtin_bit_cast(unsigned, p);
#endif
}

// ---------------- single fused kernel: 1024 blocks, 8 waves/block, one row per wave.
// Known-best config (round 5: 165.7 us total, kernel ~37 us):
//   launch_bounds(512,4) -> compiler lands at VGPR=64 (measured) -> with LDS 32KB
//   the HW fits 4 blocks/CU = 32 waves/CU, all 1024 blocks co-resident.
// DO NOT pin (512,8): allocator over-squeezes to VGPR=32, demotes the 9xf4 prefetch
// buffers, breaks double-buffering (round 7: kernel 48 us). DO NOT shrink grid to
// 512: 2 blocks/CU halves read parallelism (round 6: kernel 74-96 us).
__global__ __launch_bounds__(BLOCK, 4) void kuramoto_fused(
    const float* __restrict__ theta,
    const float* __restrict__ gam,
    const float* __restrict__ aff,
    const float* __restrict__ alp,
    const float* __restrict__ omega,
    const float* __restrict__ kappa,
    const float* __restrict__ bias,
    float* __restrict__ out)
{
    // XCD swizzle: batch-siblings x, x+8, x+16, x+24 share row-group g, differ in
    // batch b, and land on the same XCD (x%8) close in time -> bias-row L2 reuse.
    const int x   = blockIdx.x;                          // [0, 1024)
    const int low = x & 31;
    const int b   = low >> 3;
    const int g   = (x >> 5) * 8 + (low & 7);            // row-group [0, 256)
    const int i0  = g * 8;

    const int tid  = threadIdx.x;
    const int wave = tid >> 6;                           // [0, 8)
    const int lane = tid & 63;
    const int i    = i0 + wave;                          // this wave's row

    const f4* arow = (const f4*)(aff + (size_t)b * NN * NN) + (size_t)i * QQ;
    const f4* lrow = (const f4*)(alp + (size_t)b * NN * NN) + (size_t)i * QQ;
    const f4* brow = (const f4*)bias + (size_t)i * QQ;

    // ---- issue tiles 0 and 1 early: latency hides under the sincos table build ----
    f4 av[3], lv[3], bv[3];
    av[0] = __builtin_nontemporal_load(&arow[lane]);
    lv[0] = __builtin_nontemporal_load(&lrow[lane]);
    bv[0] = brow[lane];
    av[1] = __builtin_nontemporal_load(&arow[lane + 64]);
    lv[1] = __builtin_nontemporal_load(&lrow[lane + 64]);
    bv[1] = brow[lane + 64];

    // ---- build this batch's sincos table in LDS (32 KB), one quad per thread ----
    // entry (d, q) = 4 fp16 (s,c) pairs for j = 4q..4q+3; each 32-bit word is a
    // ready-made v_dot2_f32_f16 operand {sin(θj), cos(θj)}.
    __shared__ uint4 lsc[4 * QQ];
    const f4* theta4 = (const f4*)theta + (size_t)b * NN;
    {
        const int q = tid;                               // QQ == BLOCK
        float s[4][4], c[4][4];                          // [u][d]
        #pragma unroll
        for (int u = 0; u < 4; ++u) {
            const f4 th = theta4[4 * q + u];
            #pragma unroll
            for (int d = 0; d < 4; ++d) __sincosf(th[d], &s[u][d], &c[u][d]);
        }
        #pragma unroll
        for (int d = 0; d < 4; ++d) {
            uint4 w;
            w.x = pack_sc(s[0][d], c[0][d]);
            w.y = pack_sc(s[1][d], c[1][d]);
            w.z = pack_sc(s[2][d], c[2][d]);
            w.w = pack_sc(s[3][d], c[3][d]);
            lsc[d * QQ + q] = w;
        }
    }
    __syncthreads();

    f4 accU = {0.f, 0.f, 0.f, 0.f};
    f4 accV = {0.f, 0.f, 0.f, 0.f};

    #pragma unroll
    for (int jj = 0; jj < JIT; ++jj) {                   // fully unrolled: all
        const int cur = jj % 3;                          // buffer indices static
        const int q   = lane + 64 * jj;

        if (jj + 2 < JIT) {
            const int nx = (jj + 2) % 3;
            const int qn = q + 128;
            av[nx] = __builtin_nontemporal_load(&arow[qn]);
            lv[nx] = __builtin_nontemporal_load(&lrow[qn]);
            bv[nx] = brow[qn];
        }

        // (s,c) fp16 pairs for this quad, one b128 per d.
        const uint4 w0 = lsc[0 * QQ + q];
        const uint4 w1 = lsc[1 * QQ + q];
        const uint4 w2 = lsc[2 * QQ + q];
        const uint4 w3 = lsc[3 * QQ + q];
        const unsigned wq[4][4] = {
            {w0.x, w0.y, w0.z, w0.w},
            {w1.x, w1.y, w1.z, w1.w},
            {w2.x, w2.y, w2.z, w2.w},
            {w3.x, w3.y, w3.z, w3.w},
        };

        const f4 alr = lv[cur] + bv[cur];
        const f4 af  = av[cur];
        #pragma unroll
        for (int u = 0; u < 4; ++u) {
            float sa, ca;
            __sincosf(alr[u], &sa, &ca);
            const float wc = af[u] * ca;
            const float ws = af[u] * sa;
#ifdef USE_FDOT2
            // accU[d] += wc*s - ws*c ; accV[d] += ws*s + wc*c
            const h2 pw = __builtin_bit_cast(h2, __builtin_amdgcn_cvt_pkrtz(wc, -ws));
            const h2 pv = __builtin_bit_cast(h2, __builtin_amdgcn_cvt_pkrtz(ws,  wc));
            #pragma unroll
            for (int d = 0; d < 4; ++d) {
                const h2 pr = __builtin_bit_cast(h2, wq[d][u]);
                accU[d] = __builtin_amdgcn_fdot2(pw, pr, accU[d], false);
                accV[d] = __builtin_amdgcn_fdot2(pv, pr, accV[d], false);
            }
#else
            #pragma unroll
            for (int d = 0; d < 4; ++d) {
                const h2 pr = __builtin_bit_cast(h2, wq[d][u]);
                const float sj = (float)pr[0];
                const float cj = (float)pr[1];
                accU[d] += wc * sj - ws * cj;
                accV[d] += wc * cj + ws * sj;
            }
#endif
        }
    }

    // ---- wave-local shuffle reduction; no barrier needed ----
    #pragma unroll
    for (int off = 32; off >= 1; off >>= 1) {
        #pragma unroll
        for (int d = 0; d < 4; ++d) {
            accU[d] += __shfl_down(accU[d], off, 64);
            accV[d] += __shfl_down(accV[d], off, 64);
        }
    }

    if (lane == 0) {
        const f4* gam4 = (const f4*)gam;
        const f4* om4  = (const f4*)omega;
        const f4* kp4  = (const f4*)kappa;
        f4* out4       = (f4*)out;

        const size_t base = (size_t)b * NN + i;
        const f4 th = theta4[i];                         // theta4 already offset by b*NN
        const f4 gm = gam4[base];
        const f4 om = om4[i];
        const f4 kp = kp4[i];
        f4 o;
        #pragma unroll
        for (int d = 0; d < 4; ++d) {
            float si, ci;
            __sincosf(th[d], &si, &ci);                  // fp32 epilogue sincos, inline
            const float coup = (1.0f / (float)NN) * (ci * accU[d] - si * accV[d]);
            o[d] = th[d] + om[d] + kp[d] * (gm[d] - th[d]) + coup;
        }
        out4[base] = o;
    }
}

extern "C" void kernel_launch(void* const* d_in, const int* in_sizes, int n_in,
                              void* d_out, int out_size, void* d_ws, size_t ws_size,
                              hipStream_t stream) {
    const float* theta = (const float*)d_in[0];
    const float* gam   = (const float*)d_in[1];
    const float* aff   = (const float*)d_in[2];
    const float* alp   = (const float*)d_in[3];
    const float* omega = (const float*)d_in[4];
    const float* kappa = (const float*)d_in[5];
    const float* bias  = (const float*)d_in[6];
    float* out  = (float*)d_out;
    (void)d_ws; (void)ws_size;                           // workspace not used

    kuramoto_fused<<<BB * (NN / 8), BLOCK, 0, stream>>>(
        theta, gam, aff, alp, omega, kappa, bias, out);
}